// Round 5
// baseline (190.063 us; speedup 1.0000x reference)
//
#include <hip/hip_runtime.h>
#include <stdint.h>

#define EPSF 1e-6f

// ---------------------------------------------------------------------------
// DPP full-wave (64-lane) sum. After this, lane 63 holds the wave total.
// ---------------------------------------------------------------------------
__device__ __forceinline__ float wave_sum_to_lane63(float x) {
  x += __int_as_float(__builtin_amdgcn_update_dpp(0, __float_as_int(x), 0x111, 0xf, 0xf, true));  // row_shr:1
  x += __int_as_float(__builtin_amdgcn_update_dpp(0, __float_as_int(x), 0x112, 0xf, 0xf, true));  // row_shr:2
  x += __int_as_float(__builtin_amdgcn_update_dpp(0, __float_as_int(x), 0x114, 0xf, 0xf, true));  // row_shr:4
  x += __int_as_float(__builtin_amdgcn_update_dpp(0, __float_as_int(x), 0x118, 0xf, 0xf, true));  // row_shr:8
  x += __int_as_float(__builtin_amdgcn_update_dpp(0, __float_as_int(x), 0x142, 0xa, 0xf, false)); // row_bcast:15
  x += __int_as_float(__builtin_amdgcn_update_dpp(0, __float_as_int(x), 0x143, 0xc, 0xf, false)); // row_bcast:31
  return x;
}

__device__ __forceinline__ float dot4(float4 a, float4 b) {
  return a.x * b.x + a.y * b.y + a.z * b.z + a.w * b.w;
}
__device__ __forceinline__ float sum4(float4 a) {
  return (a.x + a.y) + (a.z + a.w);
}

#define RSZ 2048   // floats per stream per block (8 KB); LDS = 8*RSZ*4 = 64 KB

// ---------------------------------------------------------------------------
// Kernel 1: slot-major staged reduction.
// Rounds 1/3/4 all hit the same ~50 us wall (VALU 13%, HBM 16%, 0 conflicts,
// invariant to issue structure) -> the limiter is the ADDRESS PATTERN: the
// product pred[i]*gt[i] forces 16 streams at 256 KB (power-of-2) stride to be
// read in lockstep; they alias to the same L1-set / channel phase, and the
// few-outstanding-misses-per-set limit serializes them. Fix: never read the
// streams in lockstep. Phase A DMAs the 8 pred streams into LDS ONE AT A
// TIME (sequential contiguous 8 KB bursts); Phase B streams the 8 gt slots
// one at a time (1-deep prefetch) against the LDS-resident pred rows. At any
// instant a block touches 1-2 contiguous streams instead of 16 strided ones.
// Per batch b, block writes 66 partials:
//   [0] bg inter; [1+p*7+g] fg inter; [50+s] pred sums; [58+s] gt sums.
// ---------------------------------------------------------------------------
__global__ __launch_bounds__(256) void msl_accum(const float* __restrict__ pred,
                                                 const float* __restrict__ gt,
                                                 float* __restrict__ part, int HW) {
  __shared__ float sm[8 * RSZ];   // 64 KB; tail reduce aliases the front
  const int b    = blockIdx.y;
  const int bx   = blockIdx.x;
  const int tid  = threadIdx.x;
  const int wave = tid >> 6;
  const int lane = tid & 63;

  const size_t base = (size_t)b * 8 * (size_t)HW;
  const float* Pr = pred + base + (size_t)bx * RSZ;   // this block's pred region
  const float* Gr = gt   + base + (size_t)bx * RSZ;   // this block's gt region

  // ---- Phase A: DMA pred streams to LDS, STREAM-MAJOR (sequential bursts).
  // Stream s = 8 chunks of 1 KB; wave w issues chunks 2w, 2w+1. All waves
  // sweep streams in the same order -> block reads one contiguous stream at
  // a time. LDS dest is wave-uniform; HW adds lane*16 (m104/m108 rule).
#pragma unroll
  for (int s = 0; s < 8; ++s) {
    const float* sbase = Pr + (size_t)s * HW;
#pragma unroll
    for (int k = 0; k < 2; ++k) {
      const int chunk = wave * 2 + k;                 // 0..7
      const float* gp = sbase + chunk * 256 + lane * 4;
      float* lp = &sm[s * RSZ + chunk * 256];
      __builtin_amdgcn_global_load_lds(
          (const __attribute__((address_space(1))) void*)gp,
          (__attribute__((address_space(3))) void*)lp, 16, 0, 0);
    }
  }
  __builtin_amdgcn_s_waitcnt(0x0F70);                 // vmcnt(0)
  __syncthreads();

  // ---- Phase B: stream gt slots one at a time against LDS pred rows.
  float a_bg = 0.0f;
  float af[7][7];
  float sp[8], sg[8];
#pragma unroll
  for (int p = 0; p < 7; ++p)
#pragma unroll
    for (int g = 0; g < 7; ++g) af[p][g] = 0.0f;
#pragma unroll
  for (int s = 0; s < 8; ++s) { sp[s] = 0.0f; sg[s] = 0.0f; }

  const int t4 = tid * 4;                             // this thread's positions

  // pass g = 0: gt slot 0 + pred sums + bg product
  {
    float4 ga = *(const float4*)(Gr + t4);
    float4 gb = *(const float4*)(Gr + 1024 + t4);
    sg[0] = sum4(ga) + sum4(gb);
#pragma unroll
    for (int p = 0; p < 8; ++p) {
      float4 pa = *(const float4*)&sm[p * RSZ + t4];
      float4 pb = *(const float4*)&sm[p * RSZ + 1024 + t4];
      sp[p] = sum4(pa) + sum4(pb);
      if (p == 0) a_bg = dot4(pa, ga) + dot4(pb, gb);
    }
  }

  // passes g = 1..7, software-pipelined 1 deep (keeps <=2 gt streams
  // concurrently in flight — do NOT let the compiler hoist all of them).
  float4 ga = *(const float4*)(Gr + (size_t)1 * HW + t4);
  float4 gb = *(const float4*)(Gr + (size_t)1 * HW + 1024 + t4);
#pragma unroll 1
  for (int g = 1; g < 8; ++g) {
    float4 na, nb;
    if (g < 7) {
      na = *(const float4*)(Gr + (size_t)(g + 1) * HW + t4);
      nb = *(const float4*)(Gr + (size_t)(g + 1) * HW + 1024 + t4);
    }
    sg[g] = sum4(ga) + sum4(gb);
#pragma unroll
    for (int p = 1; p < 8; ++p) {
      float4 pa = *(const float4*)&sm[p * RSZ + t4];
      float4 pb = *(const float4*)&sm[p * RSZ + 1024 + t4];
      af[p - 1][g - 1] = fmaf(pa.x, ga.x, af[p - 1][g - 1]);
      af[p - 1][g - 1] = fmaf(pa.y, ga.y, af[p - 1][g - 1]);
      af[p - 1][g - 1] = fmaf(pa.z, ga.z, af[p - 1][g - 1]);
      af[p - 1][g - 1] = fmaf(pa.w, ga.w, af[p - 1][g - 1]);
      af[p - 1][g - 1] = fmaf(pb.x, gb.x, af[p - 1][g - 1]);
      af[p - 1][g - 1] = fmaf(pb.y, gb.y, af[p - 1][g - 1]);
      af[p - 1][g - 1] = fmaf(pb.z, gb.z, af[p - 1][g - 1]);
      af[p - 1][g - 1] = fmaf(pb.w, gb.w, af[p - 1][g - 1]);
    }
    ga = na; gb = nb;
  }

  // ---- Tail: DPP wave-reduce 66 values, cross-wave via LDS (aliases sm).
  float v[66];
  v[0] = a_bg;
#pragma unroll
  for (int p = 0; p < 7; ++p)
#pragma unroll
    for (int g = 0; g < 7; ++g) v[1 + p * 7 + g] = af[p][g];
#pragma unroll
  for (int s = 0; s < 8; ++s) { v[50 + s] = sp[s]; v[58 + s] = sg[s]; }

  __syncthreads();                                    // done reading sm as pred
  float* red = sm;                                    // red[wave*66 + k]
#pragma unroll
  for (int k = 0; k < 66; ++k) {
    float x = wave_sum_to_lane63(v[k]);
    if (lane == 63) red[wave * 66 + k] = x;
  }
  __syncthreads();

  const int row = blockIdx.y * gridDim.x + blockIdx.x;
  if (tid < 66) {
    float s = red[0 * 66 + tid] + red[1 * 66 + tid] +
              red[2 * 66 + tid] + red[3 * 66 + tid];
    part[row * 66 + tid] = s;                         // private row — no atomics
  }
}

// ---------------------------------------------------------------------------
// Kernel 2: finalize. One block, 32 lanes per batch. Sums partial rows,
// builds dice[p][g], computes the optimal-assignment VALUE via bitmask DP
// (the Hungarian match is only consumed through the sum of matched dice).
// ---------------------------------------------------------------------------
__global__ __launch_bounds__(1024) void msl_final(const float* __restrict__ part,
                                                  const int* __restrict__ nobj,
                                                  float* __restrict__ out,
                                                  int B, int RPB) {
  __shared__ float a[32][68];
  __shared__ float dp[32][130];
  __shared__ float dice[32][52];
  __shared__ float r_bg[32];
  __shared__ float r_ds[32];
  __shared__ int   r_n[32];

  const int batch = threadIdx.x >> 5;
  const int lane  = threadIdx.x & 31;
  const bool act  = (batch < B);

  if (act) {
    for (int k = lane; k < 66; k += 32) {
      float s = 0.0f;
#pragma unroll 4
      for (int r = 0; r < RPB; ++r) s += part[(batch * RPB + r) * 66 + k];
      a[batch][k] = s;
    }
  }
  __syncthreads();

  if (act) {
    for (int k = lane; k < 49; k += 32) {
      int p = k / 7, g = k % 7;
      dice[batch][k] = (2.0f * a[batch][1 + k] + EPSF) /
                       (a[batch][51 + p] + a[batch][59 + g] + EPSF);
    }
    if (lane == 0) {
      float u = a[batch][50] + a[batch][58];
      r_bg[batch] = 1.0f - (2.0f * a[batch][0] + EPSF) / (u + EPSF);
      int n = nobj[batch];
      n = n < 0 ? 0 : (n > 7 ? 7 : n);
      r_n[batch] = n;
      r_ds[batch] = 0.0f;
      dp[batch][0] = 0.0f;
    }
  }
  __syncthreads();
  const int n = act ? r_n[batch] : 0;

  for (int c = 1; c <= 7; ++c) {
    if (act && c <= n) {
      for (int mask = lane; mask < 128; mask += 32) {
        if (__popc(mask) == c) {
          float best = -1e30f;
#pragma unroll
          for (int r = 0; r < 7; ++r) {
            if (mask & (1 << r)) {
              float cand = dp[batch][mask ^ (1 << r)] + dice[batch][r * 7 + (c - 1)];
              best = fmaxf(best, cand);
            }
          }
          dp[batch][mask] = best;
        }
      }
    }
    __syncthreads();
  }

  float best = -1e30f;
  if (act && n > 0) {
    for (int mask = lane; mask < 128; mask += 32)
      if (__popc(mask) == n) best = fmaxf(best, dp[batch][mask]);
  }
#pragma unroll
  for (int off = 16; off > 0; off >>= 1)
    best = fmaxf(best, __shfl_down(best, off, 32));
  if (act && lane == 0 && n > 0) r_ds[batch] = best;
  __syncthreads();

  if (threadIdx.x == 0) {
    float bg = 0.0f, ds = 0.0f;
    int cnt = 0;
    for (int b = 0; b < B; ++b) { bg += r_bg[b]; ds += r_ds[b]; cnt += r_n[b]; }
    float fg = cnt > 0 ? ((float)cnt - ds) / (float)cnt : 0.0f;
    out[0] = bg / (float)B + fg;
  }
}

// ---------------------------------------------------------------------------
extern "C" void kernel_launch(void* const* d_in, const int* in_sizes, int n_in,
                              void* d_out, int out_size, void* d_ws, size_t ws_size,
                              hipStream_t stream) {
  const float* pred = (const float*)d_in[0];
  const float* gt   = (const float*)d_in[1];
  const int*   nobj = (const int*)d_in[2];
  float* out = (float*)d_out;

  const int B  = in_sizes[2];              // 32
  const int HW = in_sizes[0] / (B * 8);    // 65536

  float* part = (float*)d_ws;              // B * GRIDX * 66 floats (~270 KB)

  const int GRIDX = HW / RSZ;              // 32 blocks/batch -> 1024 blocks
  msl_accum<<<dim3(GRIDX, B), dim3(256), 0, stream>>>(pred, gt, part, HW);

  msl_final<<<dim3(1), dim3(32 * B), 0, stream>>>(part, nobj, out, B, GRIDX);
}

// Round 6
// 164.239 us; speedup vs baseline: 1.1572x; 1.1572x over previous
//
#include <hip/hip_runtime.h>
#include <stdint.h>

#define EPSF 1e-6f

// ---------------------------------------------------------------------------
// DPP full-wave (64-lane) sum. After this, lane 63 holds the wave total.
// ---------------------------------------------------------------------------
__device__ __forceinline__ float wave_sum_to_lane63(float x) {
  x += __int_as_float(__builtin_amdgcn_update_dpp(0, __float_as_int(x), 0x111, 0xf, 0xf, true));  // row_shr:1
  x += __int_as_float(__builtin_amdgcn_update_dpp(0, __float_as_int(x), 0x112, 0xf, 0xf, true));  // row_shr:2
  x += __int_as_float(__builtin_amdgcn_update_dpp(0, __float_as_int(x), 0x114, 0xf, 0xf, true));  // row_shr:4
  x += __int_as_float(__builtin_amdgcn_update_dpp(0, __float_as_int(x), 0x118, 0xf, 0xf, true));  // row_shr:8
  x += __int_as_float(__builtin_amdgcn_update_dpp(0, __float_as_int(x), 0x142, 0xa, 0xf, false)); // row_bcast:15
  x += __int_as_float(__builtin_amdgcn_update_dpp(0, __float_as_int(x), 0x143, 0xc, 0xf, false)); // row_bcast:31
  return x;
}

__device__ __forceinline__ float dot4(float4 a, float4 b) {
  return a.x * b.x + a.y * b.y + a.z * b.z + a.w * b.w;
}
__device__ __forceinline__ float sum4(float4 a) {
  return (a.x + a.y) + (a.z + a.w);
}

#define RSZ 2048   // floats per stream per block (8 KB); LDS = 8*RSZ*4 = 64 KB

// ---------------------------------------------------------------------------
// Kernel 1: slot-major staged reduction, round-5 theory DECONTAMINATED.
// Round 5's version spilled the 49-product accumulator to scratch (dynamic
// af[g-1] index inside a #pragma unroll 1 loop -> 93 MB scratch writes,
// VGPR=88). Here every accumulator index is a compile-time constant (g-loop
// fully unrolled) and the 8 LDS pred rows are loaded ONCE into registers
// (16 float4) and reused across all 8 gt passes.
// Structure: Phase A DMAs the 8 pred streams for this block's region into
// LDS stream-major (contiguous 8 KB bursts, global_load_lds x16B); Phase B
// reads the 8 gt streams (independent vectorized loads, compiler-scheduled)
// against the register-resident pred rows.
// Per batch b, block writes 66 partials:
//   [0] bg inter; [1+p*7+g] fg inter; [50+s] pred sums; [58+s] gt sums.
// ---------------------------------------------------------------------------
__global__ __launch_bounds__(256) void msl_accum(const float* __restrict__ pred,
                                                 const float* __restrict__ gt,
                                                 float* __restrict__ part, int HW) {
  __shared__ float sm[8 * RSZ];   // 64 KB; tail reduce aliases the front
  const int bx   = blockIdx.x;
  const int tid  = threadIdx.x;
  const int wave = tid >> 6;
  const int lane = tid & 63;

  const size_t base = (size_t)blockIdx.y * 8 * (size_t)HW;
  const float* Pr = pred + base + (size_t)bx * RSZ;   // this block's pred region
  const float* Gr = gt   + base + (size_t)bx * RSZ;   // this block's gt region

  // ---- Phase A: DMA pred streams to LDS, STREAM-MAJOR contiguous bursts.
  // Stream s = 8 chunks of 1 KB; wave w issues chunks 2w, 2w+1. LDS dest is
  // wave-uniform; HW adds lane*16 (m104/m108 rule).
#pragma unroll
  for (int s = 0; s < 8; ++s) {
    const float* sbase = Pr + (size_t)s * HW;
#pragma unroll
    for (int k = 0; k < 2; ++k) {
      const int chunk = wave * 2 + k;                 // 0..7
      const float* gp = sbase + chunk * 256 + lane * 4;
      float* lp = &sm[s * RSZ + chunk * 256];
      __builtin_amdgcn_global_load_lds(
          (const __attribute__((address_space(1))) void*)gp,
          (__attribute__((address_space(3))) void*)lp, 16, 0, 0);
    }
  }
  __builtin_amdgcn_s_waitcnt(0x0F70);                 // vmcnt(0)
  __syncthreads();

  // ---- Pred rows -> registers, ONCE (16 ds_read_b128 per thread total).
  const int t4 = tid * 4;                             // this thread's positions
  float4 pa[8], pb[8];
#pragma unroll
  for (int p = 0; p < 8; ++p) {
    pa[p] = *(const float4*)&sm[p * RSZ + t4];
    pb[p] = *(const float4*)&sm[p * RSZ + 1024 + t4];
  }

  float sp[8], sg[8];
#pragma unroll
  for (int p = 0; p < 8; ++p) sp[p] = sum4(pa[p]) + sum4(pb[p]);

  // ---- Phase B: gt streams, fully unrolled (all indices compile-time).
  float a_bg = 0.0f;
  float af[7][7];
#pragma unroll
  for (int p = 0; p < 7; ++p)
#pragma unroll
    for (int g = 0; g < 7; ++g) af[p][g] = 0.0f;

#pragma unroll
  for (int g = 0; g < 8; ++g) {
    float4 ga = *(const float4*)(Gr + (size_t)g * HW + t4);
    float4 gb = *(const float4*)(Gr + (size_t)g * HW + 1024 + t4);
    sg[g] = sum4(ga) + sum4(gb);
    if (g == 0) {
      a_bg = dot4(pa[0], ga) + dot4(pb[0], gb);
    } else {
#pragma unroll
      for (int p = 1; p < 8; ++p)
        af[p - 1][g - 1] += dot4(pa[p], ga) + dot4(pb[p], gb);
    }
  }

  // ---- Tail: DPP wave-reduce 66 values, cross-wave via LDS (aliases sm).
  float v[66];
  v[0] = a_bg;
#pragma unroll
  for (int p = 0; p < 7; ++p)
#pragma unroll
    for (int g = 0; g < 7; ++g) v[1 + p * 7 + g] = af[p][g];
#pragma unroll
  for (int s = 0; s < 8; ++s) { v[50 + s] = sp[s]; v[58 + s] = sg[s]; }

  __syncthreads();                                    // done reading sm as pred
  float* red = sm;                                    // red[wave*66 + k]
#pragma unroll
  for (int k = 0; k < 66; ++k) {
    float x = wave_sum_to_lane63(v[k]);
    if (lane == 63) red[wave * 66 + k] = x;
  }
  __syncthreads();

  const int row = blockIdx.y * gridDim.x + blockIdx.x;
  if (tid < 66) {
    float s = red[0 * 66 + tid] + red[1 * 66 + tid] +
              red[2 * 66 + tid] + red[3 * 66 + tid];
    part[row * 66 + tid] = s;                         // private row — no atomics
  }
}

// ---------------------------------------------------------------------------
// Kernel 2: finalize. One block, 32 lanes per batch. Sums partial rows,
// builds dice[p][g], computes the optimal-assignment VALUE via bitmask DP
// (the Hungarian match is only consumed through the sum of matched dice).
// ---------------------------------------------------------------------------
__global__ __launch_bounds__(1024) void msl_final(const float* __restrict__ part,
                                                  const int* __restrict__ nobj,
                                                  float* __restrict__ out,
                                                  int B, int RPB) {
  __shared__ float a[32][68];
  __shared__ float dp[32][130];
  __shared__ float dice[32][52];
  __shared__ float r_bg[32];
  __shared__ float r_ds[32];
  __shared__ int   r_n[32];

  const int batch = threadIdx.x >> 5;
  const int lane  = threadIdx.x & 31;
  const bool act  = (batch < B);

  if (act) {
    for (int k = lane; k < 66; k += 32) {
      float s = 0.0f;
#pragma unroll 4
      for (int r = 0; r < RPB; ++r) s += part[(batch * RPB + r) * 66 + k];
      a[batch][k] = s;
    }
  }
  __syncthreads();

  if (act) {
    for (int k = lane; k < 49; k += 32) {
      int p = k / 7, g = k % 7;
      dice[batch][k] = (2.0f * a[batch][1 + k] + EPSF) /
                       (a[batch][51 + p] + a[batch][59 + g] + EPSF);
    }
    if (lane == 0) {
      float u = a[batch][50] + a[batch][58];
      r_bg[batch] = 1.0f - (2.0f * a[batch][0] + EPSF) / (u + EPSF);
      int n = nobj[batch];
      n = n < 0 ? 0 : (n > 7 ? 7 : n);
      r_n[batch] = n;
      r_ds[batch] = 0.0f;
      dp[batch][0] = 0.0f;
    }
  }
  __syncthreads();
  const int n = act ? r_n[batch] : 0;

  for (int c = 1; c <= 7; ++c) {
    if (act && c <= n) {
      for (int mask = lane; mask < 128; mask += 32) {
        if (__popc(mask) == c) {
          float best = -1e30f;
#pragma unroll
          for (int r = 0; r < 7; ++r) {
            if (mask & (1 << r)) {
              float cand = dp[batch][mask ^ (1 << r)] + dice[batch][r * 7 + (c - 1)];
              best = fmaxf(best, cand);
            }
          }
          dp[batch][mask] = best;
        }
      }
    }
    __syncthreads();
  }

  float best = -1e30f;
  if (act && n > 0) {
    for (int mask = lane; mask < 128; mask += 32)
      if (__popc(mask) == n) best = fmaxf(best, dp[batch][mask]);
  }
#pragma unroll
  for (int off = 16; off > 0; off >>= 1)
    best = fmaxf(best, __shfl_down(best, off, 32));
  if (act && lane == 0 && n > 0) r_ds[batch] = best;
  __syncthreads();

  if (threadIdx.x == 0) {
    float bg = 0.0f, ds = 0.0f;
    int cnt = 0;
    for (int b = 0; b < B; ++b) { bg += r_bg[b]; ds += r_ds[b]; cnt += r_n[b]; }
    float fg = cnt > 0 ? ((float)cnt - ds) / (float)cnt : 0.0f;
    out[0] = bg / (float)B + fg;
  }
}

// ---------------------------------------------------------------------------
extern "C" void kernel_launch(void* const* d_in, const int* in_sizes, int n_in,
                              void* d_out, int out_size, void* d_ws, size_t ws_size,
                              hipStream_t stream) {
  const float* pred = (const float*)d_in[0];
  const float* gt   = (const float*)d_in[1];
  const int*   nobj = (const int*)d_in[2];
  float* out = (float*)d_out;

  const int B  = in_sizes[2];              // 32
  const int HW = in_sizes[0] / (B * 8);    // 65536

  float* part = (float*)d_ws;              // B * GRIDX * 66 floats (~270 KB)

  const int GRIDX = HW / RSZ;              // 32 blocks/batch -> 1024 blocks
  msl_accum<<<dim3(GRIDX, B), dim3(256), 0, stream>>>(pred, gt, part, HW);

  msl_final<<<dim3(1), dim3(32 * B), 0, stream>>>(part, nobj, out, B, GRIDX);
}